// Round 6
// baseline (217.222 us; speedup 1.0000x reference)
//
#include <hip/hip_runtime.h>

#define N_NODES 10000
#define N_EDGES 640000
#define N_GRAPHS 64
#define FEATS 128

#define NSLICE 64
#define EPS (N_EDGES / NSLICE)   // 10000 edges per slice
#define CAP 160                  // padded per-node edge capacity

static inline size_t align_up(size_t x, size_t a) { return (x + a - 1) & ~(a - 1); }

// ---------------------------------------------------------------------------
// 1) HIST: blocks 0..63 histogram dst-slice b into counts[b][*];
//    blocks 64..127 histogram src-slice (b-64) into scounts[b-64][*].
__global__ __launch_bounds__(256) void hist_kernel(const int* __restrict__ src,
                                                   const int* __restrict__ dst,
                                                   int* __restrict__ counts,
                                                   int* __restrict__ scounts) {
    __shared__ int h[N_NODES];
    const int tid = threadIdx.x;
    const int b = blockIdx.x;
    const bool is_dst = (b < NSLICE);
    const int slice = is_dst ? b : b - NSLICE;
    const int* col = is_dst ? dst : src;
    int* outp = (is_dst ? counts : scounts) + slice * N_NODES;

    for (int i = tid; i < N_NODES; i += 256) h[i] = 0;
    __syncthreads();
    const int4* c4 = (const int4*)(col + slice * EPS);
    for (int i = tid; i < EPS / 4; i += 256) {
        int4 v = c4[i];
        atomicAdd(&h[v.x], 1);
        atomicAdd(&h[v.y], 1);
        atomicAdd(&h[v.z], 1);
        atomicAdd(&h[v.w], 1);
    }
    __syncthreads();
    for (int i = tid; i < N_NODES; i += 256) outp[i] = h[i];
}

// ---------------------------------------------------------------------------
// 2) DEGNORM+BASE: per node n, scan counts along slices in-place into write
//    bases seeded with n*CAP; deg_in / norms / graph counts in same pass.
__global__ __launch_bounds__(256) void degnorm_base_kernel(int* __restrict__ counts,
                                                           const int* __restrict__ scounts,
                                                           const int* __restrict__ gids,
                                                           int* __restrict__ deg_in,
                                                           float* __restrict__ norm_src,
                                                           float* __restrict__ norm_dst,
                                                           int* __restrict__ graph_cnt) {
    __shared__ int gcnt[N_GRAPHS];
    const int tid = threadIdx.x;
    if (tid < N_GRAPHS) gcnt[tid] = 0;
    __syncthreads();
    int n = blockIdx.x * 256 + tid;
    if (n < N_NODES) {
        int run = n * CAP;
        for (int s = 0; s < NSLICE; s++) {
            int c = counts[s * N_NODES + n];
            counts[s * N_NODES + n] = run;
            run += c;
        }
        int di = run - n * CAP;
        int dou = 0;
        for (int s = 0; s < NSLICE; s++) dou += scounts[s * N_NODES + n];
        deg_in[n] = di;
        norm_dst[n] = rsqrtf((float)(di < 1 ? 1 : di));
        norm_src[n] = rsqrtf((float)(dou < 1 ? 1 : dou));
        atomicAdd(&gcnt[gids[n]], 1);
    }
    __syncthreads();
    if (tid < N_GRAPHS && gcnt[tid]) atomicAdd(&graph_cnt[tid], gcnt[tid]);
}

// ---------------------------------------------------------------------------
// 3) SCATTER: block s places its 10K edges via LDS cursors into the padded
//    CSR; emits sorted_ns = norm_src[src] so aggregation fma-scales free.
__global__ __launch_bounds__(256) void scatter_kernel(const int* __restrict__ src,
                                                      const int* __restrict__ dst,
                                                      const int* __restrict__ base,
                                                      const float* __restrict__ norm_src,
                                                      int* __restrict__ sorted_src,
                                                      float* __restrict__ sorted_ns) {
    __shared__ int cur[N_NODES];
    const int tid = threadIdx.x;
    const int s = blockIdx.x;
    for (int i = tid; i < N_NODES; i += 256) cur[i] = base[s * N_NODES + i];
    __syncthreads();
    const int4* s4 = (const int4*)(src + s * EPS);
    const int4* d4 = (const int4*)(dst + s * EPS);
    for (int i = tid; i < EPS / 4; i += 256) {
        int4 sv = s4[i];
        int4 dv = d4[i];
        int p;
        p = atomicAdd(&cur[dv.x], 1); sorted_src[p] = sv.x; sorted_ns[p] = norm_src[sv.x];
        p = atomicAdd(&cur[dv.y], 1); sorted_src[p] = sv.y; sorted_ns[p] = norm_src[sv.y];
        p = atomicAdd(&cur[dv.z], 1); sorted_src[p] = sv.z; sorted_ns[p] = norm_src[sv.z];
        p = atomicAdd(&cur[dv.w], 1); sorted_src[p] = sv.w; sorted_ns[p] = norm_src[sv.w];
    }
}

// ---------------------------------------------------------------------------
// 4) AGG-HALF: gather 64 of 128 features (coff = 0 or 16 in float4 units) so
//    the gathered working set (2.56 MB) fits a 4 MiB per-XCD L2.
//    One wave per dst node; 4 groups of 16 lanes fetch 4 edges/instr (1 KB).
__global__ __launch_bounds__(256) void agg_half_kernel(const float* __restrict__ X,
                                                       const int coff,
                                                       const int* __restrict__ sorted_src,
                                                       const float* __restrict__ sorted_ns,
                                                       const int* __restrict__ deg_in,
                                                       const float* __restrict__ norm_dst,
                                                       float* __restrict__ out) {
    const int tid = threadIdx.x;
    const int wave = tid >> 6, lane = tid & 63;
    const int grp = lane >> 4, l16 = lane & 15;
    const int n = blockIdx.x * 4 + wave;
    const int start = n * CAP;
    const int cnt = deg_in[n];
    const float4* __restrict__ x4 = (const float4*)X;
    float4 acc = make_float4(0.f, 0.f, 0.f, 0.f);
    int c = 0;
    for (; c + 8 <= cnt; c += 8) {
        int e0 = start + c + grp;
        int e1 = e0 + 4;
        int   i0 = sorted_src[e0]; float s0 = sorted_ns[e0];
        int   i1 = sorted_src[e1]; float s1 = sorted_ns[e1];
        float4 v0 = x4[i0 * 32 + coff + l16];
        float4 v1 = x4[i1 * 32 + coff + l16];
        acc.x = fmaf(s0, v0.x, acc.x); acc.y = fmaf(s0, v0.y, acc.y);
        acc.z = fmaf(s0, v0.z, acc.z); acc.w = fmaf(s0, v0.w, acc.w);
        acc.x = fmaf(s1, v1.x, acc.x); acc.y = fmaf(s1, v1.y, acc.y);
        acc.z = fmaf(s1, v1.z, acc.z); acc.w = fmaf(s1, v1.w, acc.w);
    }
    for (; c < cnt; c += 4) {
        int e = c + grp;
        if (e < cnt) {
            int   i = sorted_src[start + e];
            float s = sorted_ns[start + e];
            float4 v = x4[i * 32 + coff + l16];
            acc.x = fmaf(s, v.x, acc.x); acc.y = fmaf(s, v.y, acc.y);
            acc.z = fmaf(s, v.z, acc.z); acc.w = fmaf(s, v.w, acc.w);
        }
    }
    // combine the 4 groups (same feature cols across groups)
    acc.x += __shfl_xor(acc.x, 16); acc.y += __shfl_xor(acc.y, 16);
    acc.z += __shfl_xor(acc.z, 16); acc.w += __shfl_xor(acc.w, 16);
    acc.x += __shfl_xor(acc.x, 32); acc.y += __shfl_xor(acc.y, 32);
    acc.z += __shfl_xor(acc.z, 32); acc.w += __shfl_xor(acc.w, 32);
    if (grp == 0) {
        float nd = norm_dst[n];
        float4 o = make_float4(acc.x * nd, acc.y * nd, acc.z * nd, acc.w * nd);
        ((float4*)out)[n * 32 + coff + l16] = o;
    }
}

// ---------------------------------------------------------------------------
// 5) GEMM1: h = relu(A @ W + b)   (16 nodes x 128 feats per block)
__global__ __launch_bounds__(256) void gemm_relu_kernel(const float* __restrict__ A,
                                                        const float* __restrict__ W,
                                                        const float* __restrict__ bias,
                                                        float* __restrict__ out) {
    __shared__ float As[16 * FEATS];
    int tid = threadIdx.x;
    int nb = blockIdx.x * 16;
    const float4* av = (const float4*)(A + (size_t)nb * FEATS);
    float4* sv = (float4*)As;
    sv[tid]       = av[tid];
    sv[tid + 256] = av[tid + 256];
    __syncthreads();
    int fg = (tid & 31) << 2;
    int r  = tid >> 5;
    const float* a0p = As + r * FEATS;
    const float* a1p = As + (r + 8) * FEATS;
    float4 acc0 = make_float4(0.f, 0.f, 0.f, 0.f);
    float4 acc1 = make_float4(0.f, 0.f, 0.f, 0.f);
#pragma unroll 4
    for (int k = 0; k < FEATS; k++) {
        float a0 = a0p[k];
        float a1 = a1p[k];
        float4 w = *(const float4*)(W + k * FEATS + fg);
        acc0.x = fmaf(a0, w.x, acc0.x); acc0.y = fmaf(a0, w.y, acc0.y);
        acc0.z = fmaf(a0, w.z, acc0.z); acc0.w = fmaf(a0, w.w, acc0.w);
        acc1.x = fmaf(a1, w.x, acc1.x); acc1.y = fmaf(a1, w.y, acc1.y);
        acc1.z = fmaf(a1, w.z, acc1.z); acc1.w = fmaf(a1, w.w, acc1.w);
    }
    float4 bb = *(const float4*)(bias + fg);
    int gn0 = nb + r, gn1 = nb + r + 8;
    float4 o0, o1;
    o0.x = fmaxf(acc0.x + bb.x, 0.f); o0.y = fmaxf(acc0.y + bb.y, 0.f);
    o0.z = fmaxf(acc0.z + bb.z, 0.f); o0.w = fmaxf(acc0.w + bb.w, 0.f);
    o1.x = fmaxf(acc1.x + bb.x, 0.f); o1.y = fmaxf(acc1.y + bb.y, 0.f);
    o1.z = fmaxf(acc1.z + bb.z, 0.f); o1.w = fmaxf(acc1.w + bb.w, 0.f);
    *(float4*)(out + (size_t)gn0 * FEATS + fg) = o0;
    *(float4*)(out + (size_t)gn1 * FEATS + fg) = o1;
}

// ---------------------------------------------------------------------------
// 6) GEMM2+POOL: per node s = relu(A@W2+b2) . Wd ; LDS 64-bin accumulate,
//    then few global atomics per block (graph_ids sorted).
__global__ __launch_bounds__(256) void gemm_relu_pool_kernel(const float* __restrict__ A,
                                                             const float* __restrict__ W,
                                                             const float* __restrict__ bias,
                                                             const float* __restrict__ Wd,
                                                             const int* __restrict__ gids,
                                                             float* __restrict__ graph_sum) {
    __shared__ float As[16 * FEATS];
    __shared__ float bins[N_GRAPHS];
    int tid = threadIdx.x;
    int nb = blockIdx.x * 16;
    const float4* av = (const float4*)(A + (size_t)nb * FEATS);
    float4* sv = (float4*)As;
    sv[tid]       = av[tid];
    sv[tid + 256] = av[tid + 256];
    if (tid < N_GRAPHS) bins[tid] = 0.f;
    __syncthreads();
    int fg = (tid & 31) << 2;
    int r  = tid >> 5;
    const float* a0p = As + r * FEATS;
    const float* a1p = As + (r + 8) * FEATS;
    float4 acc0 = make_float4(0.f, 0.f, 0.f, 0.f);
    float4 acc1 = make_float4(0.f, 0.f, 0.f, 0.f);
#pragma unroll 4
    for (int k = 0; k < FEATS; k++) {
        float a0 = a0p[k];
        float a1 = a1p[k];
        float4 w = *(const float4*)(W + k * FEATS + fg);
        acc0.x = fmaf(a0, w.x, acc0.x); acc0.y = fmaf(a0, w.y, acc0.y);
        acc0.z = fmaf(a0, w.z, acc0.z); acc0.w = fmaf(a0, w.w, acc0.w);
        acc1.x = fmaf(a1, w.x, acc1.x); acc1.y = fmaf(a1, w.y, acc1.y);
        acc1.z = fmaf(a1, w.z, acc1.z); acc1.w = fmaf(a1, w.w, acc1.w);
    }
    float4 bb = *(const float4*)(bias + fg);
    float4 wd = *(const float4*)(Wd + fg);
    float p0 = fmaxf(acc0.x + bb.x, 0.f) * wd.x + fmaxf(acc0.y + bb.y, 0.f) * wd.y +
               fmaxf(acc0.z + bb.z, 0.f) * wd.z + fmaxf(acc0.w + bb.w, 0.f) * wd.w;
    float p1 = fmaxf(acc1.x + bb.x, 0.f) * wd.x + fmaxf(acc1.y + bb.y, 0.f) * wd.y +
               fmaxf(acc1.z + bb.z, 0.f) * wd.z + fmaxf(acc1.w + bb.w, 0.f) * wd.w;
#pragma unroll
    for (int d = 16; d >= 1; d >>= 1) {
        p0 += __shfl_down(p0, d);
        p1 += __shfl_down(p1, d);
    }
    if ((tid & 31) == 0) {
        int gn0 = nb + r, gn1 = nb + r + 8;
        atomicAdd(&bins[gids[gn0]], p0);
        atomicAdd(&bins[gids[gn1]], p1);
    }
    __syncthreads();
    if (tid < N_GRAPHS) {
        float v = bins[tid];
        if (v != 0.f) atomicAdd(&graph_sum[tid], v);
    }
}

// ---------------------------------------------------------------------------
// 7) final: out[g] = graph_sum[g] / max(cnt,1) + bd
__global__ __launch_bounds__(64) void final_kernel(const float* __restrict__ graph_sum,
                                                   const int* __restrict__ graph_cnt,
                                                   const float* __restrict__ bd,
                                                   float* __restrict__ out) {
    int g = threadIdx.x;
    if (g < N_GRAPHS) {
        out[g] = graph_sum[g] / fmaxf((float)graph_cnt[g], 1.f) + bd[0];
    }
}

// ---------------------------------------------------------------------------
extern "C" void kernel_launch(void* const* d_in, const int* in_sizes, int n_in,
                              void* d_out, int out_size, void* d_ws, size_t ws_size,
                              hipStream_t stream) {
    const float* in_feat = (const float*)d_in[0];
    const int*   src     = (const int*)d_in[1];
    const int*   dst     = (const int*)d_in[2];
    const int*   gids    = (const int*)d_in[3];
    const float* W1      = (const float*)d_in[4];
    const float* b1      = (const float*)d_in[5];
    const float* W2      = (const float*)d_in[6];
    const float* b2      = (const float*)d_in[7];
    const float* Wd      = (const float*)d_in[8];
    const float* bd      = (const float*)d_in[9];
    float* out = (float*)d_out;

    char* ws = (char*)d_ws;
    size_t off = 0;
    // --- zero zone (one tiny memset) ---
    int* graph_cnt = (int*)(ws + off); off += N_GRAPHS * 4;
    float* graph_sum = (float*)(ws + off); off += N_GRAPHS * 4;
    size_t zero_bytes = off;
    // --- non-zeroed scratch ---
    off = align_up(off, 512);
    int* counts  = (int*)(ws + off); off += (size_t)NSLICE * N_NODES * 4;   // 2.56 MB
    off = align_up(off, 512);
    int* scounts = (int*)(ws + off); off += (size_t)NSLICE * N_NODES * 4;   // 2.56 MB
    off = align_up(off, 512);
    int* deg_in  = (int*)(ws + off); off += N_NODES * 4;
    off = align_up(off, 512);
    float* norm_src = (float*)(ws + off); off += N_NODES * 4;
    off = align_up(off, 512);
    float* norm_dst = (float*)(ws + off); off += N_NODES * 4;
    off = align_up(off, 512);
    int* sorted_src = (int*)(ws + off); off += (size_t)N_NODES * CAP * 4 + 4096;  // 6.4 MB
    off = align_up(off, 512);
    float* sorted_ns = (float*)(ws + off); off += (size_t)N_NODES * CAP * 4 + 4096;
    off = align_up(off, 512);
    float* agg1 = (float*)(ws + off); off += (size_t)N_NODES * FEATS * 4;   // 5.12 MB
    off = align_up(off, 512);
    float* h    = (float*)(ws + off); off += (size_t)N_NODES * FEATS * 4;   // 5.12 MB
    off = align_up(off, 512);
    float* agg2 = (float*)(ws + off); off += (size_t)N_NODES * FEATS * 4;   // 5.12 MB
    (void)ws_size; // ~30 MB used

    hipMemsetAsync(ws, 0, zero_bytes, stream);

    // CSR build (padded; no global scan, no global atomics on the edge path)
    hist_kernel<<<2 * NSLICE, 256, 0, stream>>>(src, dst, counts, scounts);
    degnorm_base_kernel<<<(N_NODES + 255) / 256, 256, 0, stream>>>(counts, scounts, gids,
                                                                   deg_in, norm_src, norm_dst,
                                                                   graph_cnt);
    scatter_kernel<<<NSLICE, 256, 0, stream>>>(src, dst, counts, norm_src,
                                               sorted_src, sorted_ns);

    // layer 1: two L2-resident half-feature agg passes, then GEMM+relu
    agg_half_kernel<<<N_NODES / 4, 256, 0, stream>>>(in_feat, 0, sorted_src, sorted_ns,
                                                     deg_in, norm_dst, agg1);
    agg_half_kernel<<<N_NODES / 4, 256, 0, stream>>>(in_feat, 16, sorted_src, sorted_ns,
                                                     deg_in, norm_dst, agg1);
    gemm_relu_kernel<<<N_NODES / 16, 256, 0, stream>>>(agg1, W1, b1, h);

    // layer 2: same, then GEMM+relu+pool fused
    agg_half_kernel<<<N_NODES / 4, 256, 0, stream>>>(h, 0, sorted_src, sorted_ns,
                                                     deg_in, norm_dst, agg2);
    agg_half_kernel<<<N_NODES / 4, 256, 0, stream>>>(h, 16, sorted_src, sorted_ns,
                                                     deg_in, norm_dst, agg2);
    gemm_relu_pool_kernel<<<N_NODES / 16, 256, 0, stream>>>(agg2, W2, b2, Wd, gids,
                                                            graph_sum);

    final_kernel<<<1, 64, 0, stream>>>(graph_sum, graph_cnt, bd, out);
}

// Round 7
// 194.294 us; speedup vs baseline: 1.1180x; 1.1180x over previous
//
#include <hip/hip_runtime.h>

#define N_NODES 10000
#define N_EDGES 640000
#define N_GRAPHS 64
#define FEATS 128

#define NSLICE 128
#define EPS (N_EDGES / NSLICE)   // 5000 edges per slice
#define CAP 160                  // padded per-node edge capacity (max in-deg ~105)

static inline size_t align_up(size_t x, size_t a) { return (x + a - 1) & ~(a - 1); }

// ---------------------------------------------------------------------------
// 1) HIST: blocks 0..127 histogram dst-slice b into counts[b][*];
//    blocks 128..255 histogram src-slice (b-128) into scounts[b-128][*].
__global__ __launch_bounds__(256) void hist_kernel(const int* __restrict__ src,
                                                   const int* __restrict__ dst,
                                                   int* __restrict__ counts,
                                                   int* __restrict__ scounts) {
    __shared__ int h[N_NODES];
    const int tid = threadIdx.x;
    const int b = blockIdx.x;
    const bool is_dst = (b < NSLICE);
    const int slice = is_dst ? b : b - NSLICE;
    const int* col = is_dst ? dst : src;
    int* outp = (is_dst ? counts : scounts) + slice * N_NODES;

    for (int i = tid; i < N_NODES; i += 256) h[i] = 0;
    __syncthreads();
    const int4* c4 = (const int4*)(col + slice * EPS);
    for (int i = tid; i < EPS / 4; i += 256) {
        int4 v = c4[i];
        atomicAdd(&h[v.x], 1);
        atomicAdd(&h[v.y], 1);
        atomicAdd(&h[v.z], 1);
        atomicAdd(&h[v.w], 1);
    }
    __syncthreads();
    for (int i = tid; i < N_NODES; i += 256) outp[i] = h[i];
}

// ---------------------------------------------------------------------------
// 2) DEGNORM+BASE: per node n, scan counts along slices in-place into write
//    bases seeded with n*CAP; deg_in / norms / graph counts in same pass.
__global__ __launch_bounds__(256) void degnorm_base_kernel(int* __restrict__ counts,
                                                           const int* __restrict__ scounts,
                                                           const int* __restrict__ gids,
                                                           int* __restrict__ deg_in,
                                                           float* __restrict__ norm_src,
                                                           float* __restrict__ norm_dst,
                                                           int* __restrict__ graph_cnt) {
    __shared__ int gcnt[N_GRAPHS];
    const int tid = threadIdx.x;
    if (tid < N_GRAPHS) gcnt[tid] = 0;
    __syncthreads();
    int n = blockIdx.x * 256 + tid;
    if (n < N_NODES) {
        int run = n * CAP;
        for (int s = 0; s < NSLICE; s++) {
            int c = counts[s * N_NODES + n];
            counts[s * N_NODES + n] = run;
            run += c;
        }
        int di = run - n * CAP;
        int dou = 0;
        for (int s = 0; s < NSLICE; s++) dou += scounts[s * N_NODES + n];
        deg_in[n] = di;
        norm_dst[n] = rsqrtf((float)(di < 1 ? 1 : di));
        norm_src[n] = rsqrtf((float)(dou < 1 ? 1 : dou));
        atomicAdd(&gcnt[gids[n]], 1);
    }
    __syncthreads();
    if (tid < N_GRAPHS && gcnt[tid]) atomicAdd(&graph_cnt[tid], gcnt[tid]);
}

// ---------------------------------------------------------------------------
// 3) SCATTER: block s places its EPS edges via LDS cursors into the padded
//    CSR; emits sorted_ns = norm_src[src] so aggregation fma-scales free.
__global__ __launch_bounds__(256) void scatter_kernel(const int* __restrict__ src,
                                                      const int* __restrict__ dst,
                                                      const int* __restrict__ base,
                                                      const float* __restrict__ norm_src,
                                                      int* __restrict__ sorted_src,
                                                      float* __restrict__ sorted_ns) {
    __shared__ int cur[N_NODES];
    const int tid = threadIdx.x;
    const int s = blockIdx.x;
    for (int i = tid; i < N_NODES; i += 256) cur[i] = base[s * N_NODES + i];
    __syncthreads();
    const int4* s4 = (const int4*)(src + s * EPS);
    const int4* d4 = (const int4*)(dst + s * EPS);
    for (int i = tid; i < EPS / 4; i += 256) {
        int4 sv = s4[i];
        int4 dv = d4[i];
        int p;
        p = atomicAdd(&cur[dv.x], 1); sorted_src[p] = sv.x; sorted_ns[p] = norm_src[sv.x];
        p = atomicAdd(&cur[dv.y], 1); sorted_src[p] = sv.y; sorted_ns[p] = norm_src[sv.y];
        p = atomicAdd(&cur[dv.z], 1); sorted_src[p] = sv.z; sorted_ns[p] = norm_src[sv.z];
        p = atomicAdd(&cur[dv.w], 1); sorted_src[p] = sv.w; sorted_ns[p] = norm_src[sv.w];
    }
}

// ---------------------------------------------------------------------------
// 4) AGGREGATE: one wave per dst node. Each half-wave (32 lanes x float4)
//    fetches one full 512 B source row per instruction; unroll x4 keeps
//    4 KB of gathers in flight per wave (latency-concurrency fix).
__global__ __launch_bounds__(256) void aggregate_kernel(const float* __restrict__ X,
                                                        const int* __restrict__ sorted_src,
                                                        const float* __restrict__ sorted_ns,
                                                        const int* __restrict__ deg_in,
                                                        const float* __restrict__ norm_dst,
                                                        float* __restrict__ out) {
    const int tid = threadIdx.x;
    const int wave = tid >> 6, lane = tid & 63;
    const int half = lane >> 5, l32 = lane & 31;
    const int n = blockIdx.x * 4 + wave;
    const int start = n * CAP;
    const int cnt = deg_in[n];
    const float4* __restrict__ x4 = (const float4*)X;
    float4 acc = make_float4(0.f, 0.f, 0.f, 0.f);

    // half-wave `half` handles edges congruent to `half` (mod 2)
    int c = half;
    for (; c + 6 < cnt; c += 8) {
        const int e0 = start + c, e1 = e0 + 2, e2 = e0 + 4, e3 = e0 + 6;
        const int   i0 = sorted_src[e0]; const float s0 = sorted_ns[e0];
        const int   i1 = sorted_src[e1]; const float s1 = sorted_ns[e1];
        const int   i2 = sorted_src[e2]; const float s2 = sorted_ns[e2];
        const int   i3 = sorted_src[e3]; const float s3 = sorted_ns[e3];
        float4 v0 = x4[i0 * 32 + l32];
        float4 v1 = x4[i1 * 32 + l32];
        float4 v2 = x4[i2 * 32 + l32];
        float4 v3 = x4[i3 * 32 + l32];
        acc.x = fmaf(s0, v0.x, acc.x); acc.y = fmaf(s0, v0.y, acc.y);
        acc.z = fmaf(s0, v0.z, acc.z); acc.w = fmaf(s0, v0.w, acc.w);
        acc.x = fmaf(s1, v1.x, acc.x); acc.y = fmaf(s1, v1.y, acc.y);
        acc.z = fmaf(s1, v1.z, acc.z); acc.w = fmaf(s1, v1.w, acc.w);
        acc.x = fmaf(s2, v2.x, acc.x); acc.y = fmaf(s2, v2.y, acc.y);
        acc.z = fmaf(s2, v2.z, acc.z); acc.w = fmaf(s2, v2.w, acc.w);
        acc.x = fmaf(s3, v3.x, acc.x); acc.y = fmaf(s3, v3.y, acc.y);
        acc.z = fmaf(s3, v3.z, acc.z); acc.w = fmaf(s3, v3.w, acc.w);
    }
    for (; c < cnt; c += 2) {
        const int e = start + c;
        const int i = sorted_src[e];
        const float s = sorted_ns[e];
        float4 v = x4[i * 32 + l32];
        acc.x = fmaf(s, v.x, acc.x); acc.y = fmaf(s, v.y, acc.y);
        acc.z = fmaf(s, v.z, acc.z); acc.w = fmaf(s, v.w, acc.w);
    }
    // combine even/odd halves (same feature columns in both halves)
    acc.x += __shfl_xor(acc.x, 32); acc.y += __shfl_xor(acc.y, 32);
    acc.z += __shfl_xor(acc.z, 32); acc.w += __shfl_xor(acc.w, 32);
    if (half == 0) {
        const float nd = norm_dst[n];
        float4 o = make_float4(acc.x * nd, acc.y * nd, acc.z * nd, acc.w * nd);
        ((float4*)out)[n * 32 + l32] = o;
    }
}

// ---------------------------------------------------------------------------
// 5) GEMM1: h = relu(A @ W + b)   (16 nodes x 128 feats per block)
__global__ __launch_bounds__(256) void gemm_relu_kernel(const float* __restrict__ A,
                                                        const float* __restrict__ W,
                                                        const float* __restrict__ bias,
                                                        float* __restrict__ out) {
    __shared__ float As[16 * FEATS];
    int tid = threadIdx.x;
    int nb = blockIdx.x * 16;
    const float4* av = (const float4*)(A + (size_t)nb * FEATS);
    float4* sv = (float4*)As;
    sv[tid]       = av[tid];
    sv[tid + 256] = av[tid + 256];
    __syncthreads();
    int fg = (tid & 31) << 2;
    int r  = tid >> 5;
    const float* a0p = As + r * FEATS;
    const float* a1p = As + (r + 8) * FEATS;
    float4 acc0 = make_float4(0.f, 0.f, 0.f, 0.f);
    float4 acc1 = make_float4(0.f, 0.f, 0.f, 0.f);
#pragma unroll 4
    for (int k = 0; k < FEATS; k++) {
        float a0 = a0p[k];
        float a1 = a1p[k];
        float4 w = *(const float4*)(W + k * FEATS + fg);
        acc0.x = fmaf(a0, w.x, acc0.x); acc0.y = fmaf(a0, w.y, acc0.y);
        acc0.z = fmaf(a0, w.z, acc0.z); acc0.w = fmaf(a0, w.w, acc0.w);
        acc1.x = fmaf(a1, w.x, acc1.x); acc1.y = fmaf(a1, w.y, acc1.y);
        acc1.z = fmaf(a1, w.z, acc1.z); acc1.w = fmaf(a1, w.w, acc1.w);
    }
    float4 bb = *(const float4*)(bias + fg);
    int gn0 = nb + r, gn1 = nb + r + 8;
    float4 o0, o1;
    o0.x = fmaxf(acc0.x + bb.x, 0.f); o0.y = fmaxf(acc0.y + bb.y, 0.f);
    o0.z = fmaxf(acc0.z + bb.z, 0.f); o0.w = fmaxf(acc0.w + bb.w, 0.f);
    o1.x = fmaxf(acc1.x + bb.x, 0.f); o1.y = fmaxf(acc1.y + bb.y, 0.f);
    o1.z = fmaxf(acc1.z + bb.z, 0.f); o1.w = fmaxf(acc1.w + bb.w, 0.f);
    *(float4*)(out + (size_t)gn0 * FEATS + fg) = o0;
    *(float4*)(out + (size_t)gn1 * FEATS + fg) = o1;
}

// ---------------------------------------------------------------------------
// 6) GEMM2+POOL: per node s = relu(A@W2+b2) . Wd ; LDS 64-bin accumulate,
//    then few global atomics per block (graph_ids sorted).
__global__ __launch_bounds__(256) void gemm_relu_pool_kernel(const float* __restrict__ A,
                                                             const float* __restrict__ W,
                                                             const float* __restrict__ bias,
                                                             const float* __restrict__ Wd,
                                                             const int* __restrict__ gids,
                                                             float* __restrict__ graph_sum) {
    __shared__ float As[16 * FEATS];
    __shared__ float bins[N_GRAPHS];
    int tid = threadIdx.x;
    int nb = blockIdx.x * 16;
    const float4* av = (const float4*)(A + (size_t)nb * FEATS);
    float4* sv = (float4*)As;
    sv[tid]       = av[tid];
    sv[tid + 256] = av[tid + 256];
    if (tid < N_GRAPHS) bins[tid] = 0.f;
    __syncthreads();
    int fg = (tid & 31) << 2;
    int r  = tid >> 5;
    const float* a0p = As + r * FEATS;
    const float* a1p = As + (r + 8) * FEATS;
    float4 acc0 = make_float4(0.f, 0.f, 0.f, 0.f);
    float4 acc1 = make_float4(0.f, 0.f, 0.f, 0.f);
#pragma unroll 4
    for (int k = 0; k < FEATS; k++) {
        float a0 = a0p[k];
        float a1 = a1p[k];
        float4 w = *(const float4*)(W + k * FEATS + fg);
        acc0.x = fmaf(a0, w.x, acc0.x); acc0.y = fmaf(a0, w.y, acc0.y);
        acc0.z = fmaf(a0, w.z, acc0.z); acc0.w = fmaf(a0, w.w, acc0.w);
        acc1.x = fmaf(a1, w.x, acc1.x); acc1.y = fmaf(a1, w.y, acc1.y);
        acc1.z = fmaf(a1, w.z, acc1.z); acc1.w = fmaf(a1, w.w, acc1.w);
    }
    float4 bb = *(const float4*)(bias + fg);
    float4 wd = *(const float4*)(Wd + fg);
    float p0 = fmaxf(acc0.x + bb.x, 0.f) * wd.x + fmaxf(acc0.y + bb.y, 0.f) * wd.y +
               fmaxf(acc0.z + bb.z, 0.f) * wd.z + fmaxf(acc0.w + bb.w, 0.f) * wd.w;
    float p1 = fmaxf(acc1.x + bb.x, 0.f) * wd.x + fmaxf(acc1.y + bb.y, 0.f) * wd.y +
               fmaxf(acc1.z + bb.z, 0.f) * wd.z + fmaxf(acc1.w + bb.w, 0.f) * wd.w;
#pragma unroll
    for (int d = 16; d >= 1; d >>= 1) {
        p0 += __shfl_down(p0, d);
        p1 += __shfl_down(p1, d);
    }
    if ((tid & 31) == 0) {
        int gn0 = nb + r, gn1 = nb + r + 8;
        atomicAdd(&bins[gids[gn0]], p0);
        atomicAdd(&bins[gids[gn1]], p1);
    }
    __syncthreads();
    if (tid < N_GRAPHS) {
        float v = bins[tid];
        if (v != 0.f) atomicAdd(&graph_sum[tid], v);
    }
}

// ---------------------------------------------------------------------------
// 7) final: out[g] = graph_sum[g] / max(cnt,1) + bd
__global__ __launch_bounds__(64) void final_kernel(const float* __restrict__ graph_sum,
                                                   const int* __restrict__ graph_cnt,
                                                   const float* __restrict__ bd,
                                                   float* __restrict__ out) {
    int g = threadIdx.x;
    if (g < N_GRAPHS) {
        out[g] = graph_sum[g] / fmaxf((float)graph_cnt[g], 1.f) + bd[0];
    }
}

// ---------------------------------------------------------------------------
extern "C" void kernel_launch(void* const* d_in, const int* in_sizes, int n_in,
                              void* d_out, int out_size, void* d_ws, size_t ws_size,
                              hipStream_t stream) {
    const float* in_feat = (const float*)d_in[0];
    const int*   src     = (const int*)d_in[1];
    const int*   dst     = (const int*)d_in[2];
    const int*   gids    = (const int*)d_in[3];
    const float* W1      = (const float*)d_in[4];
    const float* b1      = (const float*)d_in[5];
    const float* W2      = (const float*)d_in[6];
    const float* b2      = (const float*)d_in[7];
    const float* Wd      = (const float*)d_in[8];
    const float* bd      = (const float*)d_in[9];
    float* out = (float*)d_out;

    char* ws = (char*)d_ws;
    size_t off = 0;
    // --- zero zone (one tiny memset) ---
    int* graph_cnt = (int*)(ws + off); off += N_GRAPHS * 4;
    float* graph_sum = (float*)(ws + off); off += N_GRAPHS * 4;
    size_t zero_bytes = off;
    // --- non-zeroed scratch ---
    off = align_up(off, 512);
    int* counts  = (int*)(ws + off); off += (size_t)NSLICE * N_NODES * 4;   // 5.12 MB
    off = align_up(off, 512);
    int* scounts = (int*)(ws + off); off += (size_t)NSLICE * N_NODES * 4;   // 5.12 MB
    off = align_up(off, 512);
    int* deg_in  = (int*)(ws + off); off += N_NODES * 4;
    off = align_up(off, 512);
    float* norm_src = (float*)(ws + off); off += N_NODES * 4;
    off = align_up(off, 512);
    float* norm_dst = (float*)(ws + off); off += N_NODES * 4;
    off = align_up(off, 512);
    int* sorted_src = (int*)(ws + off); off += (size_t)N_NODES * CAP * 4 + 4096;  // 6.4 MB
    off = align_up(off, 512);
    float* sorted_ns = (float*)(ws + off); off += (size_t)N_NODES * CAP * 4 + 4096;
    off = align_up(off, 512);
    float* agg1 = (float*)(ws + off); off += (size_t)N_NODES * FEATS * 4;   // 5.12 MB
    off = align_up(off, 512);
    float* h    = (float*)(ws + off); off += (size_t)N_NODES * FEATS * 4;   // 5.12 MB
    off = align_up(off, 512);
    float* agg2 = (float*)(ws + off); off += (size_t)N_NODES * FEATS * 4;   // 5.12 MB
    (void)ws_size; // ~33 MB used

    hipMemsetAsync(ws, 0, zero_bytes, stream);

    // CSR build (padded; no global scan, no global atomics on the edge path)
    hist_kernel<<<2 * NSLICE, 256, 0, stream>>>(src, dst, counts, scounts);
    degnorm_base_kernel<<<(N_NODES + 255) / 256, 256, 0, stream>>>(counts, scounts, gids,
                                                                   deg_in, norm_src, norm_dst,
                                                                   graph_cnt);
    scatter_kernel<<<NSLICE, 256, 0, stream>>>(src, dst, counts, norm_src,
                                               sorted_src, sorted_ns);

    // layer 1
    aggregate_kernel<<<N_NODES / 4, 256, 0, stream>>>(in_feat, sorted_src, sorted_ns,
                                                      deg_in, norm_dst, agg1);
    gemm_relu_kernel<<<N_NODES / 16, 256, 0, stream>>>(agg1, W1, b1, h);

    // layer 2 (+ fused pool/head)
    aggregate_kernel<<<N_NODES / 4, 256, 0, stream>>>(h, sorted_src, sorted_ns,
                                                      deg_in, norm_dst, agg2);
    gemm_relu_pool_kernel<<<N_NODES / 16, 256, 0, stream>>>(agg2, W2, b2, Wd, gids,
                                                            graph_sum);

    final_kernel<<<1, 64, 0, stream>>>(graph_sum, graph_cnt, bd, out);
}

// Round 8
// 193.991 us; speedup vs baseline: 1.1198x; 1.0016x over previous
//
#include <hip/hip_runtime.h>

#define N_NODES 10000
#define N_EDGES 640000
#define N_GRAPHS 64
#define FEATS 128

#define NSLICE 64
#define EPS (N_EDGES / NSLICE)   // 10000 edges per slice
#define CAP 160                  // padded per-node edge capacity (max in-deg ~112)

static inline size_t align_up(size_t x, size_t a) { return (x + a - 1) & ~(a - 1); }

// ---------------------------------------------------------------------------
// 1) HIST: blocks 0..63 histogram dst-slice b into counts[b][*];
//    blocks 64..127 histogram src-slice (b-64) into scounts[b-64][*].
__global__ __launch_bounds__(256) void hist_kernel(const int* __restrict__ src,
                                                   const int* __restrict__ dst,
                                                   int* __restrict__ counts,
                                                   int* __restrict__ scounts) {
    __shared__ int h[N_NODES];
    const int tid = threadIdx.x;
    const int b = blockIdx.x;
    const bool is_dst = (b < NSLICE);
    const int slice = is_dst ? b : b - NSLICE;
    const int* col = is_dst ? dst : src;
    int* outp = (is_dst ? counts : scounts) + slice * N_NODES;

    for (int i = tid; i < N_NODES; i += 256) h[i] = 0;
    __syncthreads();
    const int4* c4 = (const int4*)(col + slice * EPS);
    for (int i = tid; i < EPS / 4; i += 256) {
        int4 v = c4[i];
        atomicAdd(&h[v.x], 1);
        atomicAdd(&h[v.y], 1);
        atomicAdd(&h[v.z], 1);
        atomicAdd(&h[v.w], 1);
    }
    __syncthreads();
    for (int i = tid; i < N_NODES; i += 256) outp[i] = h[i];
}

// ---------------------------------------------------------------------------
// 2) DEGNORM+BASE: per node n, scan counts along slices in-place into write
//    bases seeded with n*CAP; deg_in / norms / graph counts in same pass.
__global__ __launch_bounds__(256) void degnorm_base_kernel(int* __restrict__ counts,
                                                           const int* __restrict__ scounts,
                                                           const int* __restrict__ gids,
                                                           int* __restrict__ deg_in,
                                                           float* __restrict__ norm_src,
                                                           float* __restrict__ norm_dst,
                                                           int* __restrict__ graph_cnt) {
    __shared__ int gcnt[N_GRAPHS];
    const int tid = threadIdx.x;
    if (tid < N_GRAPHS) gcnt[tid] = 0;
    __syncthreads();
    int n = blockIdx.x * 256 + tid;
    if (n < N_NODES) {
        int run = n * CAP;
        for (int s = 0; s < NSLICE; s++) {
            int c = counts[s * N_NODES + n];
            counts[s * N_NODES + n] = run;
            run += c;
        }
        int di = run - n * CAP;
        int dou = 0;
        for (int s = 0; s < NSLICE; s++) dou += scounts[s * N_NODES + n];
        deg_in[n] = di;
        norm_dst[n] = rsqrtf((float)(di < 1 ? 1 : di));
        norm_src[n] = rsqrtf((float)(dou < 1 ? 1 : dou));
        atomicAdd(&gcnt[gids[n]], 1);
    }
    __syncthreads();
    if (tid < N_GRAPHS && gcnt[tid]) atomicAdd(&graph_cnt[tid], gcnt[tid]);
}

// ---------------------------------------------------------------------------
// 3) SCATTER: block s places its EPS edges via LDS cursors into the padded
//    CSR (src index only — norm_src is folded into the node features).
__global__ __launch_bounds__(256) void scatter_kernel(const int* __restrict__ src,
                                                      const int* __restrict__ dst,
                                                      const int* __restrict__ base,
                                                      int* __restrict__ sorted_src) {
    __shared__ int cur[N_NODES];
    const int tid = threadIdx.x;
    const int s = blockIdx.x;
    for (int i = tid; i < N_NODES; i += 256) cur[i] = base[s * N_NODES + i];
    __syncthreads();
    const int4* s4 = (const int4*)(src + s * EPS);
    const int4* d4 = (const int4*)(dst + s * EPS);
    for (int i = tid; i < EPS / 4; i += 256) {
        int4 sv = s4[i];
        int4 dv = d4[i];
        int p;
        p = atomicAdd(&cur[dv.x], 1); sorted_src[p] = sv.x;
        p = atomicAdd(&cur[dv.y], 1); sorted_src[p] = sv.y;
        p = atomicAdd(&cur[dv.z], 1); sorted_src[p] = sv.z;
        p = atomicAdd(&cur[dv.w], 1); sorted_src[p] = sv.w;
    }
}

// ---------------------------------------------------------------------------
// 4) PRESCALE: xs = in_feat * norm_src (layer-1 input; layer-2 input is
//    pre-scaled by GEMM1's epilogue instead).
__global__ __launch_bounds__(256) void prescale_kernel(const float* __restrict__ in_feat,
                                                       const float* __restrict__ norm_src,
                                                       float* __restrict__ xs) {
    int i = blockIdx.x * 256 + threadIdx.x; // over N_NODES*FEATS/4 = 320000
    if (i < N_NODES * (FEATS / 4)) {
        int n = i >> 5;
        float4 v = ((const float4*)in_feat)[i];
        float s = norm_src[n];
        v.x *= s; v.y *= s; v.z *= s; v.w *= s;
        ((float4*)xs)[i] = v;
    }
}

// ---------------------------------------------------------------------------
// 5) AGGREGATE: one wave per dst node; half-wave (32 lanes x float4) fetches
//    a full 512 B row per instr; unroll x8 -> 8 KB of gathers in flight/wave.
//    Input is pre-scaled by norm_src, so the inner loop is pure adds.
__global__ __launch_bounds__(256) void aggregate_kernel(const float* __restrict__ X,
                                                        const int* __restrict__ sorted_src,
                                                        const int* __restrict__ deg_in,
                                                        const float* __restrict__ norm_dst,
                                                        float* __restrict__ out) {
    const int tid = threadIdx.x;
    const int wave = tid >> 6, lane = tid & 63;
    const int half = lane >> 5, l32 = lane & 31;
    const int n = blockIdx.x * 4 + wave;
    const int start = n * CAP;
    const int cnt = deg_in[n];
    const float4* __restrict__ x4 = (const float4*)X;
    float4 acc = make_float4(0.f, 0.f, 0.f, 0.f);

    // half-wave `half` handles edges congruent to `half` (mod 2)
    int c = half;
    for (; c + 14 < cnt; c += 16) {
        int idx[8];
#pragma unroll
        for (int k = 0; k < 8; k++) idx[k] = sorted_src[start + c + 2 * k];
        float4 v[8];
#pragma unroll
        for (int k = 0; k < 8; k++) v[k] = x4[idx[k] * 32 + l32];
#pragma unroll
        for (int k = 0; k < 8; k++) {
            acc.x += v[k].x; acc.y += v[k].y; acc.z += v[k].z; acc.w += v[k].w;
        }
    }
    for (; c < cnt; c += 2) {
        int i = sorted_src[start + c];
        float4 v = x4[i * 32 + l32];
        acc.x += v.x; acc.y += v.y; acc.z += v.z; acc.w += v.w;
    }
    // combine even/odd halves (same feature columns in both halves)
    acc.x += __shfl_xor(acc.x, 32); acc.y += __shfl_xor(acc.y, 32);
    acc.z += __shfl_xor(acc.z, 32); acc.w += __shfl_xor(acc.w, 32);
    if (half == 0) {
        const float nd = norm_dst[n];
        float4 o = make_float4(acc.x * nd, acc.y * nd, acc.z * nd, acc.w * nd);
        ((float4*)out)[n * 32 + l32] = o;
    }
}

// ---------------------------------------------------------------------------
// 6) GEMM1: h = norm_src ⊙ relu(A @ W + b)  (scale folded into epilogue so
//    layer 2 gathers a pre-scaled input). 16 nodes x 128 feats per block.
__global__ __launch_bounds__(256) void gemm_relu_scale_kernel(const float* __restrict__ A,
                                                              const float* __restrict__ W,
                                                              const float* __restrict__ bias,
                                                              const float* __restrict__ scale,
                                                              float* __restrict__ out) {
    __shared__ float As[16 * FEATS];
    int tid = threadIdx.x;
    int nb = blockIdx.x * 16;
    const float4* av = (const float4*)(A + (size_t)nb * FEATS);
    float4* sv = (float4*)As;
    sv[tid]       = av[tid];
    sv[tid + 256] = av[tid + 256];
    __syncthreads();
    int fg = (tid & 31) << 2;
    int r  = tid >> 5;
    const float* a0p = As + r * FEATS;
    const float* a1p = As + (r + 8) * FEATS;
    float4 acc0 = make_float4(0.f, 0.f, 0.f, 0.f);
    float4 acc1 = make_float4(0.f, 0.f, 0.f, 0.f);
#pragma unroll 4
    for (int k = 0; k < FEATS; k++) {
        float a0 = a0p[k];
        float a1 = a1p[k];
        float4 w = *(const float4*)(W + k * FEATS + fg);
        acc0.x = fmaf(a0, w.x, acc0.x); acc0.y = fmaf(a0, w.y, acc0.y);
        acc0.z = fmaf(a0, w.z, acc0.z); acc0.w = fmaf(a0, w.w, acc0.w);
        acc1.x = fmaf(a1, w.x, acc1.x); acc1.y = fmaf(a1, w.y, acc1.y);
        acc1.z = fmaf(a1, w.z, acc1.z); acc1.w = fmaf(a1, w.w, acc1.w);
    }
    float4 bb = *(const float4*)(bias + fg);
    int gn0 = nb + r, gn1 = nb + r + 8;
    float s0 = scale[gn0], s1 = scale[gn1];
    float4 o0, o1;
    o0.x = fmaxf(acc0.x + bb.x, 0.f) * s0; o0.y = fmaxf(acc0.y + bb.y, 0.f) * s0;
    o0.z = fmaxf(acc0.z + bb.z, 0.f) * s0; o0.w = fmaxf(acc0.w + bb.w, 0.f) * s0;
    o1.x = fmaxf(acc1.x + bb.x, 0.f) * s1; o1.y = fmaxf(acc1.y + bb.y, 0.f) * s1;
    o1.z = fmaxf(acc1.z + bb.z, 0.f) * s1; o1.w = fmaxf(acc1.w + bb.w, 0.f) * s1;
    *(float4*)(out + (size_t)gn0 * FEATS + fg) = o0;
    *(float4*)(out + (size_t)gn1 * FEATS + fg) = o1;
}

// ---------------------------------------------------------------------------
// 7) GEMM2+POOL: per node s = relu(A@W2+b2) . Wd ; LDS 64-bin accumulate,
//    then few global atomics per block (graph_ids sorted).
__global__ __launch_bounds__(256) void gemm_relu_pool_kernel(const float* __restrict__ A,
                                                             const float* __restrict__ W,
                                                             const float* __restrict__ bias,
                                                             const float* __restrict__ Wd,
                                                             const int* __restrict__ gids,
                                                             float* __restrict__ graph_sum) {
    __shared__ float As[16 * FEATS];
    __shared__ float bins[N_GRAPHS];
    int tid = threadIdx.x;
    int nb = blockIdx.x * 16;
    const float4* av = (const float4*)(A + (size_t)nb * FEATS);
    float4* sv = (float4*)As;
    sv[tid]       = av[tid];
    sv[tid + 256] = av[tid + 256];
    if (tid < N_GRAPHS) bins[tid] = 0.f;
    __syncthreads();
    int fg = (tid & 31) << 2;
    int r  = tid >> 5;
    const float* a0p = As + r * FEATS;
    const float* a1p = As + (r + 8) * FEATS;
    float4 acc0 = make_float4(0.f, 0.f, 0.f, 0.f);
    float4 acc1 = make_float4(0.f, 0.f, 0.f, 0.f);
#pragma unroll 4
    for (int k = 0; k < FEATS; k++) {
        float a0 = a0p[k];
        float a1 = a1p[k];
        float4 w = *(const float4*)(W + k * FEATS + fg);
        acc0.x = fmaf(a0, w.x, acc0.x); acc0.y = fmaf(a0, w.y, acc0.y);
        acc0.z = fmaf(a0, w.z, acc0.z); acc0.w = fmaf(a0, w.w, acc0.w);
        acc1.x = fmaf(a1, w.x, acc1.x); acc1.y = fmaf(a1, w.y, acc1.y);
        acc1.z = fmaf(a1, w.z, acc1.z); acc1.w = fmaf(a1, w.w, acc1.w);
    }
    float4 bb = *(const float4*)(bias + fg);
    float4 wd = *(const float4*)(Wd + fg);
    float p0 = fmaxf(acc0.x + bb.x, 0.f) * wd.x + fmaxf(acc0.y + bb.y, 0.f) * wd.y +
               fmaxf(acc0.z + bb.z, 0.f) * wd.z + fmaxf(acc0.w + bb.w, 0.f) * wd.w;
    float p1 = fmaxf(acc1.x + bb.x, 0.f) * wd.x + fmaxf(acc1.y + bb.y, 0.f) * wd.y +
               fmaxf(acc1.z + bb.z, 0.f) * wd.z + fmaxf(acc1.w + bb.w, 0.f) * wd.w;
#pragma unroll
    for (int d = 16; d >= 1; d >>= 1) {
        p0 += __shfl_down(p0, d);
        p1 += __shfl_down(p1, d);
    }
    if ((tid & 31) == 0) {
        int gn0 = nb + r, gn1 = nb + r + 8;
        atomicAdd(&bins[gids[gn0]], p0);
        atomicAdd(&bins[gids[gn1]], p1);
    }
    __syncthreads();
    if (tid < N_GRAPHS) {
        float v = bins[tid];
        if (v != 0.f) atomicAdd(&graph_sum[tid], v);
    }
}

// ---------------------------------------------------------------------------
// 8) final: out[g] = graph_sum[g] / max(cnt,1) + bd
__global__ __launch_bounds__(64) void final_kernel(const float* __restrict__ graph_sum,
                                                   const int* __restrict__ graph_cnt,
                                                   const float* __restrict__ bd,
                                                   float* __restrict__ out) {
    int g = threadIdx.x;
    if (g < N_GRAPHS) {
        out[g] = graph_sum[g] / fmaxf((float)graph_cnt[g], 1.f) + bd[0];
    }
}

// ---------------------------------------------------------------------------
extern "C" void kernel_launch(void* const* d_in, const int* in_sizes, int n_in,
                              void* d_out, int out_size, void* d_ws, size_t ws_size,
                              hipStream_t stream) {
    const float* in_feat = (const float*)d_in[0];
    const int*   src     = (const int*)d_in[1];
    const int*   dst     = (const int*)d_in[2];
    const int*   gids    = (const int*)d_in[3];
    const float* W1      = (const float*)d_in[4];
    const float* b1      = (const float*)d_in[5];
    const float* W2      = (const float*)d_in[6];
    const float* b2      = (const float*)d_in[7];
    const float* Wd      = (const float*)d_in[8];
    const float* bd      = (const float*)d_in[9];
    float* out = (float*)d_out;

    char* ws = (char*)d_ws;
    size_t off = 0;
    // --- zero zone (one tiny memset) ---
    int* graph_cnt = (int*)(ws + off); off += N_GRAPHS * 4;
    float* graph_sum = (float*)(ws + off); off += N_GRAPHS * 4;
    size_t zero_bytes = off;
    // --- non-zeroed scratch ---
    off = align_up(off, 512);
    int* counts  = (int*)(ws + off); off += (size_t)NSLICE * N_NODES * 4;   // 2.56 MB
    off = align_up(off, 512);
    int* scounts = (int*)(ws + off); off += (size_t)NSLICE * N_NODES * 4;   // 2.56 MB
    off = align_up(off, 512);
    int* deg_in  = (int*)(ws + off); off += N_NODES * 4;
    off = align_up(off, 512);
    float* norm_src = (float*)(ws + off); off += N_NODES * 4;
    off = align_up(off, 512);
    float* norm_dst = (float*)(ws + off); off += N_NODES * 4;
    off = align_up(off, 512);
    int* sorted_src = (int*)(ws + off); off += (size_t)N_NODES * CAP * 4 + 4096;  // 6.4 MB
    off = align_up(off, 512);
    float* xs   = (float*)(ws + off); off += (size_t)N_NODES * FEATS * 4;   // 5.12 MB
    off = align_up(off, 512);
    float* agg1 = (float*)(ws + off); off += (size_t)N_NODES * FEATS * 4;   // 5.12 MB
    off = align_up(off, 512);
    float* h    = (float*)(ws + off); off += (size_t)N_NODES * FEATS * 4;   // 5.12 MB
    off = align_up(off, 512);
    float* agg2 = (float*)(ws + off); off += (size_t)N_NODES * FEATS * 4;   // 5.12 MB
    (void)ws_size; // ~32 MB used

    hipMemsetAsync(ws, 0, zero_bytes, stream);

    // CSR build (padded; no global scan, no global atomics on the edge path)
    hist_kernel<<<2 * NSLICE, 256, 0, stream>>>(src, dst, counts, scounts);
    degnorm_base_kernel<<<(N_NODES + 255) / 256, 256, 0, stream>>>(counts, scounts, gids,
                                                                   deg_in, norm_src, norm_dst,
                                                                   graph_cnt);
    scatter_kernel<<<NSLICE, 256, 0, stream>>>(src, dst, counts, sorted_src);
    prescale_kernel<<<(N_NODES * (FEATS / 4) + 255) / 256, 256, 0, stream>>>(in_feat,
                                                                             norm_src, xs);

    // layer 1 (h is written pre-scaled by norm_src for layer 2)
    aggregate_kernel<<<N_NODES / 4, 256, 0, stream>>>(xs, sorted_src, deg_in, norm_dst, agg1);
    gemm_relu_scale_kernel<<<N_NODES / 16, 256, 0, stream>>>(agg1, W1, b1, norm_src, h);

    // layer 2 (+ fused pool/head)
    aggregate_kernel<<<N_NODES / 4, 256, 0, stream>>>(h, sorted_src, deg_in, norm_dst, agg2);
    gemm_relu_pool_kernel<<<N_NODES / 16, 256, 0, stream>>>(agg2, W2, b2, Wd, gids,
                                                            graph_sum);

    final_kernel<<<1, 64, 0, stream>>>(graph_sum, graph_cnt, bd, out);
}

// Round 9
// 175.321 us; speedup vs baseline: 1.2390x; 1.1065x over previous
//
#include <hip/hip_runtime.h>
#include <hip/hip_fp16.h>

#define N_NODES 10000
#define N_EDGES 640000
#define N_GRAPHS 64
#define FEATS 128

#define NSLICE 64
#define EPS (N_EDGES / NSLICE)   // 10000 edges per slice
#define CAP 160                  // padded per-node edge capacity (max in-deg ~112)

static inline size_t align_up(size_t x, size_t a) { return (x + a - 1) & ~(a - 1); }

// ---------------------------------------------------------------------------
// 1) HIST: blocks 0..63 histogram dst-slice b into counts[b][*];
//    blocks 64..127 histogram src-slice (b-64) into scounts[b-64][*].
__global__ __launch_bounds__(256) void hist_kernel(const int* __restrict__ src,
                                                   const int* __restrict__ dst,
                                                   int* __restrict__ counts,
                                                   int* __restrict__ scounts) {
    __shared__ int h[N_NODES];
    const int tid = threadIdx.x;
    const int b = blockIdx.x;
    const bool is_dst = (b < NSLICE);
    const int slice = is_dst ? b : b - NSLICE;
    const int* col = is_dst ? dst : src;
    int* outp = (is_dst ? counts : scounts) + slice * N_NODES;

    for (int i = tid; i < N_NODES; i += 256) h[i] = 0;
    __syncthreads();
    const int4* c4 = (const int4*)(col + slice * EPS);
    for (int i = tid; i < EPS / 4; i += 256) {
        int4 v = c4[i];
        atomicAdd(&h[v.x], 1);
        atomicAdd(&h[v.y], 1);
        atomicAdd(&h[v.z], 1);
        atomicAdd(&h[v.w], 1);
    }
    __syncthreads();
    for (int i = tid; i < N_NODES; i += 256) outp[i] = h[i];
}

// ---------------------------------------------------------------------------
// 2) DEGNORM+BASE: per node n, scan counts along slices in-place into write
//    bases seeded with n*CAP; deg_in / norms / graph counts in same pass.
__global__ __launch_bounds__(256) void degnorm_base_kernel(int* __restrict__ counts,
                                                           const int* __restrict__ scounts,
                                                           const int* __restrict__ gids,
                                                           int* __restrict__ deg_in,
                                                           float* __restrict__ norm_src,
                                                           float* __restrict__ norm_dst,
                                                           int* __restrict__ graph_cnt) {
    __shared__ int gcnt[N_GRAPHS];
    const int tid = threadIdx.x;
    if (tid < N_GRAPHS) gcnt[tid] = 0;
    __syncthreads();
    int n = blockIdx.x * 256 + tid;
    if (n < N_NODES) {
        int run = n * CAP;
        for (int s = 0; s < NSLICE; s++) {
            int c = counts[s * N_NODES + n];
            counts[s * N_NODES + n] = run;
            run += c;
        }
        int di = run - n * CAP;
        int dou = 0;
        for (int s = 0; s < NSLICE; s++) dou += scounts[s * N_NODES + n];
        deg_in[n] = di;
        norm_dst[n] = rsqrtf((float)(di < 1 ? 1 : di));
        norm_src[n] = rsqrtf((float)(dou < 1 ? 1 : dou));
        atomicAdd(&gcnt[gids[n]], 1);
    }
    __syncthreads();
    if (tid < N_GRAPHS && gcnt[tid]) atomicAdd(&graph_cnt[tid], gcnt[tid]);
}

// ---------------------------------------------------------------------------
// 3) SCATTER: block s places its EPS edges via LDS cursors into the padded
//    CSR (src index only — norm_src is folded into the node features).
__global__ __launch_bounds__(256) void scatter_kernel(const int* __restrict__ src,
                                                      const int* __restrict__ dst,
                                                      const int* __restrict__ base,
                                                      int* __restrict__ sorted_src) {
    __shared__ int cur[N_NODES];
    const int tid = threadIdx.x;
    const int s = blockIdx.x;
    for (int i = tid; i < N_NODES; i += 256) cur[i] = base[s * N_NODES + i];
    __syncthreads();
    const int4* s4 = (const int4*)(src + s * EPS);
    const int4* d4 = (const int4*)(dst + s * EPS);
    for (int i = tid; i < EPS / 4; i += 256) {
        int4 sv = s4[i];
        int4 dv = d4[i];
        int p;
        p = atomicAdd(&cur[dv.x], 1); sorted_src[p] = sv.x;
        p = atomicAdd(&cur[dv.y], 1); sorted_src[p] = sv.y;
        p = atomicAdd(&cur[dv.z], 1); sorted_src[p] = sv.z;
        p = atomicAdd(&cur[dv.w], 1); sorted_src[p] = sv.w;
    }
}

// ---------------------------------------------------------------------------
// 4) PRESCALE: xs_h = fp16(in_feat * norm_src). 2.56 MB -> L2-resident.
__global__ __launch_bounds__(256) void prescale_kernel(const float* __restrict__ in_feat,
                                                       const float* __restrict__ norm_src,
                                                       __half* __restrict__ xs) {
    int i = blockIdx.x * 256 + threadIdx.x; // over N_NODES*FEATS/4 = 320000
    if (i < N_NODES * (FEATS / 4)) {
        int n = i >> 5;
        float4 v = ((const float4*)in_feat)[i];
        float s = norm_src[n];
        __half2 h0 = __floats2half2_rn(v.x * s, v.y * s);
        __half2 h1 = __floats2half2_rn(v.z * s, v.w * s);
        __half2* o = (__half2*)(xs + (size_t)i * 4);
        o[0] = h0; o[1] = h1;
    }
}

// ---------------------------------------------------------------------------
// 5) AGGREGATE (fp16 in, fp32 out): one wave per dst node. Quarter-wave
//    (16 lanes x 16 B) fetches one 256 B fp16 row per instr -> 4 edges per
//    wave instruction; unroll x4 keeps 16 rows (4 KB) in flight per wave.
__global__ __launch_bounds__(256) void aggregate_kernel(const __half* __restrict__ X,
                                                        const int* __restrict__ sorted_src,
                                                        const int* __restrict__ deg_in,
                                                        const float* __restrict__ norm_dst,
                                                        float* __restrict__ out) {
    const int tid = threadIdx.x;
    const int wave = tid >> 6, lane = tid & 63;
    const int grp = lane >> 4, l16 = lane & 15;
    const int n = blockIdx.x * 4 + wave;
    const int start = n * CAP;
    const int cnt = deg_in[n];
    const uint4* __restrict__ x4 = (const uint4*)X;  // row = 16 uint4 (256 B)
    float acc[8] = {0.f, 0.f, 0.f, 0.f, 0.f, 0.f, 0.f, 0.f};

    // group `grp` handles edges congruent to `grp` (mod 4)
    int c = grp;
    for (; c + 12 < cnt; c += 16) {
        int idx[4];
#pragma unroll
        for (int k = 0; k < 4; k++) idx[k] = sorted_src[start + c + 4 * k];
        uint4 v[4];
#pragma unroll
        for (int k = 0; k < 4; k++) v[k] = x4[idx[k] * 16 + l16];
#pragma unroll
        for (int k = 0; k < 4; k++) {
            const __half2* hp = (const __half2*)&v[k];
#pragma unroll
            for (int j = 0; j < 4; j++) {
                float2 f = __half22float2(hp[j]);
                acc[2 * j]     += f.x;
                acc[2 * j + 1] += f.y;
            }
        }
    }
    for (; c < cnt; c += 4) {
        uint4 v = x4[sorted_src[start + c] * 16 + l16];
        const __half2* hp = (const __half2*)&v;
#pragma unroll
        for (int j = 0; j < 4; j++) {
            float2 f = __half22float2(hp[j]);
            acc[2 * j]     += f.x;
            acc[2 * j + 1] += f.y;
        }
    }
    // combine the 4 groups (same feature columns in all groups)
#pragma unroll
    for (int j = 0; j < 8; j++) {
        acc[j] += __shfl_xor(acc[j], 16);
        acc[j] += __shfl_xor(acc[j], 32);
    }
    if (grp == 0) {
        const float nd = norm_dst[n];
        float4 o0 = make_float4(acc[0] * nd, acc[1] * nd, acc[2] * nd, acc[3] * nd);
        float4 o1 = make_float4(acc[4] * nd, acc[5] * nd, acc[6] * nd, acc[7] * nd);
        float4* op = (float4*)(out + (size_t)n * FEATS + l16 * 8);
        op[0] = o0; op[1] = o1;
    }
}

// ---------------------------------------------------------------------------
// 6) GEMM1: h = fp16(norm_src ⊙ relu(A @ W + b))  (scale + fp16 cast in the
//    epilogue so layer 2 gathers an L2-resident pre-scaled input).
__global__ __launch_bounds__(256) void gemm_relu_scale_kernel(const float* __restrict__ A,
                                                              const float* __restrict__ W,
                                                              const float* __restrict__ bias,
                                                              const float* __restrict__ scale,
                                                              __half* __restrict__ out) {
    __shared__ float As[16 * FEATS];
    int tid = threadIdx.x;
    int nb = blockIdx.x * 16;
    const float4* av = (const float4*)(A + (size_t)nb * FEATS);
    float4* sv = (float4*)As;
    sv[tid]       = av[tid];
    sv[tid + 256] = av[tid + 256];
    __syncthreads();
    int fg = (tid & 31) << 2;
    int r  = tid >> 5;
    const float* a0p = As + r * FEATS;
    const float* a1p = As + (r + 8) * FEATS;
    float4 acc0 = make_float4(0.f, 0.f, 0.f, 0.f);
    float4 acc1 = make_float4(0.f, 0.f, 0.f, 0.f);
#pragma unroll 4
    for (int k = 0; k < FEATS; k++) {
        float a0 = a0p[k];
        float a1 = a1p[k];
        float4 w = *(const float4*)(W + k * FEATS + fg);
        acc0.x = fmaf(a0, w.x, acc0.x); acc0.y = fmaf(a0, w.y, acc0.y);
        acc0.z = fmaf(a0, w.z, acc0.z); acc0.w = fmaf(a0, w.w, acc0.w);
        acc1.x = fmaf(a1, w.x, acc1.x); acc1.y = fmaf(a1, w.y, acc1.y);
        acc1.z = fmaf(a1, w.z, acc1.z); acc1.w = fmaf(a1, w.w, acc1.w);
    }
    float4 bb = *(const float4*)(bias + fg);
    int gn0 = nb + r, gn1 = nb + r + 8;
    float s0 = scale[gn0], s1 = scale[gn1];
    __half2 h00 = __floats2half2_rn(fmaxf(acc0.x + bb.x, 0.f) * s0,
                                    fmaxf(acc0.y + bb.y, 0.f) * s0);
    __half2 h01 = __floats2half2_rn(fmaxf(acc0.z + bb.z, 0.f) * s0,
                                    fmaxf(acc0.w + bb.w, 0.f) * s0);
    __half2 h10 = __floats2half2_rn(fmaxf(acc1.x + bb.x, 0.f) * s1,
                                    fmaxf(acc1.y + bb.y, 0.f) * s1);
    __half2 h11 = __floats2half2_rn(fmaxf(acc1.z + bb.z, 0.f) * s1,
                                    fmaxf(acc1.w + bb.w, 0.f) * s1);
    __half2* o0 = (__half2*)(out + (size_t)gn0 * FEATS + fg);
    __half2* o1 = (__half2*)(out + (size_t)gn1 * FEATS + fg);
    o0[0] = h00; o0[1] = h01;
    o1[0] = h10; o1[1] = h11;
}

// ---------------------------------------------------------------------------
// 7) GEMM2+POOL: per node s = relu(A@W2+b2) . Wd ; LDS 64-bin accumulate,
//    then few global atomics per block (graph_ids sorted).
__global__ __launch_bounds__(256) void gemm_relu_pool_kernel(const float* __restrict__ A,
                                                             const float* __restrict__ W,
                                                             const float* __restrict__ bias,
                                                             const float* __restrict__ Wd,
                                                             const int* __restrict__ gids,
                                                             float* __restrict__ graph_sum) {
    __shared__ float As[16 * FEATS];
    __shared__ float bins[N_GRAPHS];
    int tid = threadIdx.x;
    int nb = blockIdx.x * 16;
    const float4* av = (const float4*)(A + (size_t)nb * FEATS);
    float4* sv = (float4*)As;
    sv[tid]       = av[tid];
    sv[tid + 256] = av[tid + 256];
    if (tid < N_GRAPHS) bins[tid] = 0.f;
    __syncthreads();
    int fg = (tid & 31) << 2;
    int r  = tid >> 5;
    const float* a0p = As + r * FEATS;
    const float* a1p = As + (r + 8) * FEATS;
    float4 acc0 = make_float4(0.f, 0.f, 0.f, 0.f);
    float4 acc1 = make_float4(0.f, 0.f, 0.f, 0.f);
#pragma unroll 4
    for (int k = 0; k < FEATS; k++) {
        float a0 = a0p[k];
        float a1 = a1p[k];
        float4 w = *(const float4*)(W + k * FEATS + fg);
        acc0.x = fmaf(a0, w.x, acc0.x); acc0.y = fmaf(a0, w.y, acc0.y);
        acc0.z = fmaf(a0, w.z, acc0.z); acc0.w = fmaf(a0, w.w, acc0.w);
        acc1.x = fmaf(a1, w.x, acc1.x); acc1.y = fmaf(a1, w.y, acc1.y);
        acc1.z = fmaf(a1, w.z, acc1.z); acc1.w = fmaf(a1, w.w, acc1.w);
    }
    float4 bb = *(const float4*)(bias + fg);
    float4 wd = *(const float4*)(Wd + fg);
    float p0 = fmaxf(acc0.x + bb.x, 0.f) * wd.x + fmaxf(acc0.y + bb.y, 0.f) * wd.y +
               fmaxf(acc0.z + bb.z, 0.f) * wd.z + fmaxf(acc0.w + bb.w, 0.f) * wd.w;
    float p1 = fmaxf(acc1.x + bb.x, 0.f) * wd.x + fmaxf(acc1.y + bb.y, 0.f) * wd.y +
               fmaxf(acc1.z + bb.z, 0.f) * wd.z + fmaxf(acc1.w + bb.w, 0.f) * wd.w;
#pragma unroll
    for (int d = 16; d >= 1; d >>= 1) {
        p0 += __shfl_down(p0, d);
        p1 += __shfl_down(p1, d);
    }
    if ((tid & 31) == 0) {
        int gn0 = nb + r, gn1 = nb + r + 8;
        atomicAdd(&bins[gids[gn0]], p0);
        atomicAdd(&bins[gids[gn1]], p1);
    }
    __syncthreads();
    if (tid < N_GRAPHS) {
        float v = bins[tid];
        if (v != 0.f) atomicAdd(&graph_sum[tid], v);
    }
}

// ---------------------------------------------------------------------------
// 8) final: out[g] = graph_sum[g] / max(cnt,1) + bd
__global__ __launch_bounds__(64) void final_kernel(const float* __restrict__ graph_sum,
                                                   const int* __restrict__ graph_cnt,
                                                   const float* __restrict__ bd,
                                                   float* __restrict__ out) {
    int g = threadIdx.x;
    if (g < N_GRAPHS) {
        out[g] = graph_sum[g] / fmaxf((float)graph_cnt[g], 1.f) + bd[0];
    }
}

// ---------------------------------------------------------------------------
extern "C" void kernel_launch(void* const* d_in, const int* in_sizes, int n_in,
                              void* d_out, int out_size, void* d_ws, size_t ws_size,
                              hipStream_t stream) {
    const float* in_feat = (const float*)d_in[0];
    const int*   src     = (const int*)d_in[1];
    const int*   dst     = (const int*)d_in[2];
    const int*   gids    = (const int*)d_in[3];
    const float* W1      = (const float*)d_in[4];
    const float* b1      = (const float*)d_in[5];
    const float* W2      = (const float*)d_in[6];
    const float* b2      = (const float*)d_in[7];
    const float* Wd      = (const float*)d_in[8];
    const float* bd      = (const float*)d_in[9];
    float* out = (float*)d_out;

    char* ws = (char*)d_ws;
    size_t off = 0;
    // --- zero zone (one tiny memset) ---
    int* graph_cnt = (int*)(ws + off); off += N_GRAPHS * 4;
    float* graph_sum = (float*)(ws + off); off += N_GRAPHS * 4;
    size_t zero_bytes = off;
    // --- non-zeroed scratch ---
    off = align_up(off, 512);
    int* counts  = (int*)(ws + off); off += (size_t)NSLICE * N_NODES * 4;   // 2.56 MB
    off = align_up(off, 512);
    int* scounts = (int*)(ws + off); off += (size_t)NSLICE * N_NODES * 4;   // 2.56 MB
    off = align_up(off, 512);
    int* deg_in  = (int*)(ws + off); off += N_NODES * 4;
    off = align_up(off, 512);
    float* norm_src = (float*)(ws + off); off += N_NODES * 4;
    off = align_up(off, 512);
    float* norm_dst = (float*)(ws + off); off += N_NODES * 4;
    off = align_up(off, 512);
    int* sorted_src = (int*)(ws + off); off += (size_t)N_NODES * CAP * 4 + 4096;  // 6.4 MB
    off = align_up(off, 512);
    __half* xs  = (__half*)(ws + off); off += (size_t)N_NODES * FEATS * 2;  // 2.56 MB
    off = align_up(off, 512);
    __half* h   = (__half*)(ws + off); off += (size_t)N_NODES * FEATS * 2;  // 2.56 MB
    off = align_up(off, 512);
    float* agg1 = (float*)(ws + off); off += (size_t)N_NODES * FEATS * 4;   // 5.12 MB
    off = align_up(off, 512);
    float* agg2 = (float*)(ws + off); off += (size_t)N_NODES * FEATS * 4;   // 5.12 MB
    (void)ws_size; // ~27 MB used

    hipMemsetAsync(ws, 0, zero_bytes, stream);

    // CSR build (padded; no global scan, no global atomics on the edge path)
    hist_kernel<<<2 * NSLICE, 256, 0, stream>>>(src, dst, counts, scounts);
    degnorm_base_kernel<<<(N_NODES + 255) / 256, 256, 0, stream>>>(counts, scounts, gids,
                                                                   deg_in, norm_src, norm_dst,
                                                                   graph_cnt);
    scatter_kernel<<<NSLICE, 256, 0, stream>>>(src, dst, counts, sorted_src);
    prescale_kernel<<<(N_NODES * (FEATS / 4) + 255) / 256, 256, 0, stream>>>(in_feat,
                                                                             norm_src, xs);

    // layer 1 (h is written pre-scaled by norm_src, fp16, for layer 2)
    aggregate_kernel<<<N_NODES / 4, 256, 0, stream>>>(xs, sorted_src, deg_in, norm_dst, agg1);
    gemm_relu_scale_kernel<<<N_NODES / 16, 256, 0, stream>>>(agg1, W1, b1, norm_src, h);

    // layer 2 (+ fused pool/head)
    aggregate_kernel<<<N_NODES / 4, 256, 0, stream>>>(h, sorted_src, deg_in, norm_dst, agg2);
    gemm_relu_pool_kernel<<<N_NODES / 16, 256, 0, stream>>>(agg2, W2, b2, Wd, gids,
                                                            graph_sum);

    final_kernel<<<1, 64, 0, stream>>>(graph_sum, graph_cnt, bd, out);
}